// Round 6
// baseline (68.634 us; speedup 1.0000x reference)
//
#include <hip/hip_runtime.h>
#include <math.h>

// SemiConvModel: max-plus 1xK conv (K=15, parabolic weights), reduced over
// C_IN=3, broadcast to C_OUT=16 identical channels.
// out[b,c,h,w] = max_n( max_cin x[b,cin,h,w+n-7] + w[n] ),  w[n] = -(n-7)^2/(4*scale)
//
// Round 6: two-phase split.
//   K1: base[B,H,W] = result (16.8 MB) -> d_ws.   reads 48MB, writes 16.8MB.
//   K2: out[b,c,:,:] = base[b,:,:] broadcast, each block writes one contiguous
//       128KB span (fill-like linear write stream), base read is L3-resident.

#define BB   16
#define CIN  3
#define HH   512
#define WW   512
#define COUT 16
#define KK   15
#define HALF 7
#define ROWS 4          // rows per block = waves per block (K1)
#define TPB  256

typedef float floatx4 __attribute__((ext_vector_type(4)));

// ---------------- K1: compute base = maxplus(max_c x) ----------------
// LDS row layout: p in [8,520) holds xmax[p-8]; [0,8) and [520,528) = -inf.

__global__ __launch_bounds__(TPB) void semiconv_base_kernel(
    const float* __restrict__ x, const float* __restrict__ scale_p,
    float* __restrict__ base)
{
    __shared__ __align__(16) float m[ROWS][528];
    const int t  = threadIdx.x;
    const int wv = t >> 6;            // wave index = row within group
    const int i  = t & 63;            // lane
    const int g  = blockIdx.x;        // 0 .. 2047
    const int b  = g >> 7;
    const int h  = ((g & 127) << 2) + wv;

    const float inv4s = 0.25f / scale_p[0];

    const float* xrow = x + ((size_t)(b * CIN) * HH + h) * (size_t)WW;
    const size_t cs   = (size_t)HH * WW;
    {
        const float* p0 = xrow + 4 * i;
        floatx4 a0 = *(const floatx4*)(p0);
        floatx4 b0 = *(const floatx4*)(p0 + 256);
        floatx4 a1 = *(const floatx4*)(p0 + cs);
        floatx4 b1 = *(const floatx4*)(p0 + cs + 256);
        floatx4 a2 = *(const floatx4*)(p0 + 2 * cs);
        floatx4 b2 = *(const floatx4*)(p0 + 2 * cs + 256);
        floatx4 s0, s1;
        s0.x = fmaxf(fmaxf(a0.x, a1.x), a2.x);
        s0.y = fmaxf(fmaxf(a0.y, a1.y), a2.y);
        s0.z = fmaxf(fmaxf(a0.z, a1.z), a2.z);
        s0.w = fmaxf(fmaxf(a0.w, a1.w), a2.w);
        s1.x = fmaxf(fmaxf(b0.x, b1.x), b2.x);
        s1.y = fmaxf(fmaxf(b0.y, b1.y), b2.y);
        s1.z = fmaxf(fmaxf(b0.z, b1.z), b2.z);
        s1.w = fmaxf(fmaxf(b0.w, b1.w), b2.w);
        *(floatx4*)&m[wv][8 + 4 * i]       = s0;
        *(floatx4*)&m[wv][8 + 256 + 4 * i] = s1;
    }
    {
        const floatx4 ninf = {-INFINITY, -INFINITY, -INFINITY, -INFINITY};
        if (i < 2)       *(floatx4*)&m[wv][4 * i]              = ninf;
        else if (i > 61) *(floatx4*)&m[wv][520 + 4 * (i - 62)] = ninf;
    }
    // wave-lockstep: lgkmcnt(0) orders ds_write -> ds_read within the wave
    asm volatile("s_waitcnt lgkmcnt(0)" ::: "memory");

    float wt[KK];
    #pragma unroll
    for (int n = 0; n < KK; ++n) {
        float z = (float)(n - HALF);
        wt[n] = -(z * z) * inv4s;
    }

    float* orow = base + ((size_t)b * HH + h) * (size_t)WW + 4 * i;
    #pragma unroll
    for (int s = 0; s < 2; ++s) {
        const int w0 = s * 256 + 4 * i;
        float v[20];
        #pragma unroll
        for (int k = 0; k < 5; ++k) {
            floatx4 a = *(const floatx4*)&m[wv][w0 + 4 * k];
            v[4 * k + 0] = a.x; v[4 * k + 1] = a.y;
            v[4 * k + 2] = a.z; v[4 * k + 3] = a.w;
        }
        float res[4];
        #pragma unroll
        for (int j = 0; j < 4; ++j) {
            float best = v[j + 1] + wt[0];
            #pragma unroll
            for (int n = 1; n < KK; ++n)
                best = fmaxf(best, v[j + n + 1] + wt[n]);
            res[j] = best;
        }
        floatx4 rv;
        rv.x = res[0]; rv.y = res[1]; rv.z = res[2]; rv.w = res[3];
        *(floatx4*)(orow + s * 256) = rv;
    }
}

// ---------------- K2: linear broadcast base -> 16 channels ----------------
// Block b owns one contiguous 128KB span of out (8 blocks per channel plane).
// grid = 16*16*8 = 2048 blocks; per thread 32 float4 copies, fully coalesced.

__global__ __launch_bounds__(TPB) void broadcast_kernel(
    const float* __restrict__ base, float* __restrict__ out)
{
    const int t        = threadIdx.x;
    const int blk      = blockIdx.x;       // 0..2047
    const int plane_id = blk >> 3;         // (b*16 + c), 0..255
    const int sub      = blk & 7;          // eighth of a plane
    const int b        = plane_id >> 4;

    const floatx4* src = (const floatx4*)base + ((size_t)b << 16) + (sub << 13) + t;
    floatx4*       dst = (floatx4*)out + ((size_t)plane_id << 16) + (sub << 13) + t;

    #pragma unroll 8
    for (int k = 0; k < 32; ++k) {
        dst[k * 256] = src[k * 256];
    }
}

extern "C" void kernel_launch(void* const* d_in, const int* in_sizes, int n_in,
                              void* d_out, int out_size, void* d_ws, size_t ws_size,
                              hipStream_t stream) {
    const float* x     = (const float*)d_in[0];
    const float* scale = (const float*)d_in[1];
    float* out         = (float*)d_out;
    float* base        = (float*)d_ws;     // 16*512*512*4 = 16.8 MB scratch

    hipLaunchKernelGGL(semiconv_base_kernel, dim3(BB * HH / ROWS), dim3(TPB),
                       0, stream, x, scale, base);
    hipLaunchKernelGGL(broadcast_kernel, dim3(BB * COUT * 8), dim3(TPB),
                       0, stream, base, out);
}

// Round 7
// 60.414 us; speedup vs baseline: 1.1361x; 1.1361x over previous
//
#include <hip/hip_runtime.h>
#include <math.h>

// SemiConvModel: max-plus 1xK conv (K=15, parabolic weights), reduced over
// C_IN=3, broadcast to C_OUT=16 identical channels.
// out[b,c,h,w] = max_n( max_cin x[b,cin,h,w+n-7] + w[n] ),  w[n] = -(n-7)^2/(4*scale)
//
// Round 7: A/B the nontemporal flag — round-5 kernel with PLAIN stores
// (through-L2 write-combining path, same as fillBufferAligned). Everything
// else identical: ROWS=4, TPB=256, wave-independent pipelines, grid 2048.

#define BB   16
#define CIN  3
#define HH   512
#define WW   512
#define COUT 16
#define KK   15
#define HALF 7
#define ROWS 4          // rows per block = waves per block
#define TPB  256

typedef float floatx4 __attribute__((ext_vector_type(4)));

// LDS row layout: index p in [8, 520) holds xmax[p-8]; [0,8) and [520,528)
// are -inf pads. Left pad of 8 keeps all float4 accesses 16B-aligned.

__global__ __launch_bounds__(TPB) void semiconv_kernel(
    const float* __restrict__ x, const float* __restrict__ scale_p,
    float* __restrict__ out)
{
    __shared__ __align__(16) float m[ROWS][528];
    const int t  = threadIdx.x;
    const int wv = t >> 6;            // wave index = row within group
    const int i  = t & 63;            // lane
    const int g  = blockIdx.x;        // 0 .. 2047
    const int b  = g >> 7;            // 128 row-groups per batch
    const int h  = ((g & 127) << 2) + wv;

    const float inv4s = 0.25f / scale_p[0];

    // ---- stage this wave's row: channel max, two dense 256-col segments ----
    const float*  xrow = x + ((size_t)(b * CIN) * HH + h) * (size_t)WW;
    const size_t  cs   = (size_t)HH * WW;        // channel stride (floats)
    {
        const float* p0 = xrow + 4 * i;
        floatx4 a0 = *(const floatx4*)(p0);
        floatx4 b0 = *(const floatx4*)(p0 + 256);
        floatx4 a1 = *(const floatx4*)(p0 + cs);
        floatx4 b1 = *(const floatx4*)(p0 + cs + 256);
        floatx4 a2 = *(const floatx4*)(p0 + 2 * cs);
        floatx4 b2 = *(const floatx4*)(p0 + 2 * cs + 256);
        floatx4 s0, s1;
        s0.x = fmaxf(fmaxf(a0.x, a1.x), a2.x);
        s0.y = fmaxf(fmaxf(a0.y, a1.y), a2.y);
        s0.z = fmaxf(fmaxf(a0.z, a1.z), a2.z);
        s0.w = fmaxf(fmaxf(a0.w, a1.w), a2.w);
        s1.x = fmaxf(fmaxf(b0.x, b1.x), b2.x);
        s1.y = fmaxf(fmaxf(b0.y, b1.y), b2.y);
        s1.z = fmaxf(fmaxf(b0.z, b1.z), b2.z);
        s1.w = fmaxf(fmaxf(b0.w, b1.w), b2.w);
        *(floatx4*)&m[wv][8 + 4 * i]       = s0;
        *(floatx4*)&m[wv][8 + 256 + 4 * i] = s1;
    }
    // -inf pads, written by edge lanes of this wave
    {
        const floatx4 ninf = {-INFINITY, -INFINITY, -INFINITY, -INFINITY};
        if (i < 2)       *(floatx4*)&m[wv][4 * i]              = ninf;  // [0,8)
        else if (i > 61) *(floatx4*)&m[wv][520 + 4 * (i - 62)] = ninf;  // [520,528)
    }
    // wave is lockstep: lgkmcnt(0) orders ds_write -> ds_read, no __syncthreads
    asm volatile("s_waitcnt lgkmcnt(0)" ::: "memory");

    // ---- parabolic weights (exact for scale=1: integer^2 * 0.25) ----
    float wt[KK];
    #pragma unroll
    for (int n = 0; n < KK; ++n) {
        float z = (float)(n - HALF);
        wt[n] = -(z * z) * inv4s;
    }

    // ---- compute: two 4-output segments per lane ----
    floatx4 rv[2];
    #pragma unroll
    for (int s = 0; s < 2; ++s) {
        const int w0 = s * 256 + 4 * i;    // first output col of this segment
        float v[20];                       // cols [w0-8, w0+12)
        #pragma unroll
        for (int k = 0; k < 5; ++k) {
            floatx4 a = *(const floatx4*)&m[wv][w0 + 4 * k];
            v[4 * k + 0] = a.x; v[4 * k + 1] = a.y;
            v[4 * k + 2] = a.z; v[4 * k + 3] = a.w;
        }
        float res[4];
        #pragma unroll
        for (int j = 0; j < 4; ++j) {
            float best = v[j + 1] + wt[0];
            #pragma unroll
            for (int n = 1; n < KK; ++n)
                best = fmaxf(best, v[j + n + 1] + wt[n]);
            res[j] = best;
        }
        rv[s].x = res[0]; rv[s].y = res[1]; rv[s].z = res[2]; rv[s].w = res[3];
    }

    // ---- PLAIN stores (A/B vs nt): 16 channels x 2 dense segments ----
    float* ob = out + ((size_t)(b * COUT) * HH + h) * (size_t)WW + 4 * i;
    #pragma unroll
    for (int c = 0; c < COUT; ++c) {
        float* p = ob + (size_t)c * cs;
        *(floatx4*)p         = rv[0];
        *(floatx4*)(p + 256) = rv[1];
    }
}

extern "C" void kernel_launch(void* const* d_in, const int* in_sizes, int n_in,
                              void* d_out, int out_size, void* d_ws, size_t ws_size,
                              hipStream_t stream) {
    const float* x     = (const float*)d_in[0];
    const float* scale = (const float*)d_in[1];
    float* out         = (float*)d_out;

    dim3 grid(BB * HH / ROWS);   // 2048 blocks
    dim3 block(TPB);
    hipLaunchKernelGGL(semiconv_kernel, grid, block, 0, stream, x, scale, out);
}

// Round 8
// 56.472 us; speedup vs baseline: 1.2154x; 1.0698x over previous
//
#include <hip/hip_runtime.h>
#include <math.h>

// SemiConvModel: max-plus 1xK conv (K=15, parabolic weights), reduced over
// C_IN=3, broadcast to C_OUT=16 identical channels.
// out[b,c,h,w] = max_n( max_cin x[b,cin,h,w+n-7] + w[n] ),  w[n] = -(n-7)^2/(4*scale)
//
// Round 8: FINAL — revert to best-known config (round 3, 56.37 us):
// ROWS=4, TPB=512, LDS-staged channel-max rows, nontemporal float4 stores.
// A/B history: 16KB chunks -7%, linear-write split -18%, plain stores -7%,
// wave-private pipelines null => this is the optimum found; ~90% of the
// D2D-copy-calibrated HBM ceiling (318.8 MB min traffic at 5.66 TB/s).

#define BB   16
#define CIN  3
#define HH   512
#define WW   512
#define COUT 16
#define KK   15
#define HALF 7
#define ROWS 4          // rows per block
#define TPB  512        // threads per block

typedef float floatx4 __attribute__((ext_vector_type(4)));

// LDS row layout: index p in [8, 520) holds xmax[p-8]; p in [0,8) and
// [520,528) are -inf pads. Left pad of 8 (not 7) keeps float4 ops aligned.

__global__ __launch_bounds__(TPB) void semiconv_kernel(
    const float* __restrict__ x, const float* __restrict__ scale_p,
    float* __restrict__ out)
{
    __shared__ __align__(16) float m[ROWS][528];
    const int t  = threadIdx.x;
    const int g  = blockIdx.x;        // 0 .. B*H/ROWS - 1  (2048)
    const int b  = g >> 7;            // 128 row-groups per batch
    const int h0 = (g & 127) << 2;    // first row of the group

    const float inv4s = 0.25f / scale_p[0];

    // ---- -inf pads: 4 rows x 16 pad slots = 64 entries ----
    if (t < 64) {
        int r = t >> 4;
        int q = t & 15;
        int p = (q < 8) ? q : (512 + q);   // 0..7 and 520..527
        m[r][p] = -INFINITY;
    }

    // ---- vectorized channel-max staging: 4 rows x 128 float4 = 512 threads ----
    {
        int r = t >> 7;                // row within group
        int i = t & 127;               // float4 index within row
        const floatx4* xr = (const floatx4*)(x + ((size_t)(b * CIN) * HH + (h0 + r)) * (size_t)WW) + i;
        const size_t cs = (size_t)HH * WW / 4;   // channel stride in float4s
        floatx4 a0 = xr[0];
        floatx4 a1 = xr[cs];
        floatx4 a2 = xr[2 * cs];
        floatx4 mx;
        mx.x = fmaxf(fmaxf(a0.x, a1.x), a2.x);
        mx.y = fmaxf(fmaxf(a0.y, a1.y), a2.y);
        mx.z = fmaxf(fmaxf(a0.z, a1.z), a2.z);
        mx.w = fmaxf(fmaxf(a0.w, a1.w), a2.w);
        *(floatx4*)&m[r][8 + 4 * i] = mx;
    }
    __syncthreads();

    // ---- parabolic weights (exact for scale=1: integer^2 * 0.25) ----
    float wt[KK];
    #pragma unroll
    for (int n = 0; n < KK; ++n) {
        float z = (float)(n - HALF);
        wt[n] = -(z * z) * inv4s;
    }

    // ---- compute: thread -> (row r, 4 outputs at w0) ----
    const int r  = t >> 7;
    const int w0 = (t & 127) << 2;
    float v[20];
    #pragma unroll
    for (int k = 0; k < 5; ++k) {
        floatx4 a = *(const floatx4*)&m[r][w0 + 4 * k];
        v[4 * k + 0] = a.x; v[4 * k + 1] = a.y;
        v[4 * k + 2] = a.z; v[4 * k + 3] = a.w;
    }
    // output w0+i uses input w0+i+n-7 -> LDS p = w0 + (i+n+1)
    float res[4];
    #pragma unroll
    for (int i = 0; i < 4; ++i) {
        float best = v[i + 1] + wt[0];
        #pragma unroll
        for (int n = 1; n < KK; ++n)
            best = fmaxf(best, v[i + n + 1] + wt[n]);
        res[i] = best;
    }
    floatx4 rv;
    rv.x = res[0]; rv.y = res[1]; rv.z = res[2]; rv.w = res[3];

    // ---- nontemporal stores: 16 channels, 8KB contiguous per channel/block ----
    float* ob = out + ((size_t)(b * COUT) * HH + (h0 + r)) * (size_t)WW + w0;
    #pragma unroll
    for (int c = 0; c < COUT; ++c) {
        __builtin_nontemporal_store(rv, (floatx4*)(ob + (size_t)c * HH * WW));
    }
}

extern "C" void kernel_launch(void* const* d_in, const int* in_sizes, int n_in,
                              void* d_out, int out_size, void* d_ws, size_t ws_size,
                              hipStream_t stream) {
    const float* x     = (const float*)d_in[0];
    const float* scale = (const float*)d_in[1];
    float* out         = (float*)d_out;

    dim3 grid(BB * HH / ROWS);   // 2048 blocks
    dim3 block(TPB);
    hipLaunchKernelGGL(semiconv_kernel, grid, block, 0, stream, x, scale, out);
}